// Round 3
// baseline (1624.003 us; speedup 1.0000x reference)
//
#include <hip/hip_runtime.h>

#define NROWS 131072
#define KC    128
#define DIM   510
#define BLK   256

typedef float vf2 __attribute__((ext_vector_type(2)));

// One thread per row. acc[128] lives in VGPRs (k-loop fully unrolled).
// Codebook accesses use block-uniform indices -> compiler emits scalar
// s_load (sK$), so the main loop has no LDS traffic and no barriers.
// Numerics: identical fp32 ascending-d FMA chains and fp64 c_sq as the
// round-1 kernel (bitwise), so argmin matches np everywhere.
__global__ __launch_bounds__(BLK, 2) void vq2(const float* __restrict__ z,
                                              const float* __restrict__ cb,
                                              float* __restrict__ out) {
    __shared__ float csq[KC];
    __shared__ int   kbest[BLK];

    const int tid  = threadIdx.x;
    const int wave = tid >> 6;
    const int lane = tid & 63;

    // ---- Phase 0: c_sq in fp64, bitwise-identical to round-1 csq_kernel ----
    for (int kk = 0; kk < 32; ++kk) {
        const int k = wave * 32 + kk;
        double s = 0.0;
        for (int d = lane; d < DIM; d += 64) {
            double v = (double)cb[k * DIM + d];
            s += v * v;
        }
        for (int m = 32; m > 0; m >>= 1) s += __shfl_down(s, m);
        if (lane == 0) csq[k] = (float)s;
    }
    __syncthreads();

    // ---- Phase 1: distances. One row per thread, acc[128] in registers ----
    const long row = (long)blockIdx.x * BLK + tid;
    const float2* zr = (const float2*)(z + row * (long)DIM);   // rows 8B-aligned

    float acc[KC];
    float zsq = 0.f;
#pragma unroll
    for (int k = 0; k < KC; ++k) acc[k] = 0.f;

    // 31 full chunks of 16 floats (8 float2), then a 14-float tail
    for (int ch = 0; ch < 31; ++ch) {
        const int p0 = ch * 8;
        float2 zv[8];
#pragma unroll
        for (int i = 0; i < 8; ++i) zv[i] = zr[p0 + i];
#pragma unroll
        for (int i = 0; i < 8; ++i) {
            zsq = fmaf(zv[i].x, zv[i].x, zsq);
            zsq = fmaf(zv[i].y, zv[i].y, zsq);
        }
#pragma unroll
        for (int k = 0; k < KC; ++k) {
            const float2* cr = (const float2*)(cb + (long)k * DIM);  // uniform -> s_load
#pragma unroll
            for (int i = 0; i < 8; ++i) {
                float2 cv = cr[p0 + i];
                acc[k] = fmaf(zv[i].x, cv.x, acc[k]);
                acc[k] = fmaf(zv[i].y, cv.y, acc[k]);
            }
        }
    }
    {   // tail: d = 496..509 (7 float2)
        const int p0 = 248;
        float2 zv[7];
#pragma unroll
        for (int i = 0; i < 7; ++i) zv[i] = zr[p0 + i];
#pragma unroll
        for (int i = 0; i < 7; ++i) {
            zsq = fmaf(zv[i].x, zv[i].x, zsq);
            zsq = fmaf(zv[i].y, zv[i].y, zsq);
        }
#pragma unroll
        for (int k = 0; k < KC; ++k) {
            const float2* cr = (const float2*)(cb + (long)k * DIM);
#pragma unroll
            for (int i = 0; i < 7; ++i) {
                float2 cv = cr[p0 + i];
                acc[k] = fmaf(zv[i].x, cv.x, acc[k]);
                acc[k] = fmaf(zv[i].y, cv.y, acc[k]);
            }
        }
    }

    // ---- argmin: same rounding sequence as np: (zsq - 2*dot) + csq ----
    float bd = 3.0e38f;
    int   bk = 0;
#pragma unroll
    for (int k = 0; k < KC; ++k) {
        float t    = zsq - 2.0f * acc[k];
        float dist = t + csq[k];
        if (dist < bd) { bd = dist; bk = k; }   // strict <: lowest k wins ties
    }
    kbest[tid] = bk;
    __syncthreads();

    // ---- Phase 2: cooperative coalesced gather, nontemporal stores ----
    const long rowBase = (long)blockIdx.x * BLK;
    for (int r = wave; r < BLK; r += 4) {
        const int k = kbest[r];
        const float2* src = (const float2*)(cb + (long)k * DIM);
        float* dst = out + (rowBase + r) * (long)DIM;
        for (int d2 = lane; d2 < DIM / 2; d2 += 64) {
            float2 v = src[d2];
            vf2 vv = { v.x, v.y };
            __builtin_nontemporal_store(vv, (vf2*)(dst + 2 * d2));
        }
    }
}

extern "C" void kernel_launch(void* const* d_in, const int* in_sizes, int n_in,
                              void* d_out, int out_size, void* d_ws, size_t ws_size,
                              hipStream_t stream) {
    const float* z  = (const float*)d_in[0];
    const float* cb = (const float*)d_in[1];
    float* out = (float*)d_out;
    vq2<<<NROWS / BLK, BLK, 0, stream>>>(z, cb, out);
}